// Round 8
// baseline (299.536 us; speedup 1.0000x reference)
//
#include <hip/hip_runtime.h>
#include <hip/hip_bf16.h>
#include <math.h>

#define NEG_SLOPE 0.2f
#define WSZ 384   // slot window per aggr block (8 nodes, mean 136 slots)
#define GZ  32    // LDS guard entries: consumer index <= wsz + 30 provably

typedef __bf16 bf16x8 __attribute__((ext_vector_type(8)));
typedef float f32x4 __attribute__((ext_vector_type(4)));

__device__ __forceinline__ float lrelu(float x) { return x > 0.f ? x : NEG_SLOPE * x; }

__device__ __forceinline__ unsigned short f2bfu(float f) {
    unsigned int ua = __float_as_uint(f);
    return (unsigned short)((ua + 0x7fffu + ((ua >> 16) & 1u)) >> 16);
}
__device__ __forceinline__ float bfu2f(unsigned short u) {
    return __uint_as_float(((unsigned int)u) << 16);
}
__device__ __forceinline__ float bf_lo(unsigned int u) { return __uint_as_float(u << 16); }
__device__ __forceinline__ float bf_hi(unsigned int u) { return __uint_as_float(u & 0xffff0000u); }

// ---------------------------------------------------------------------------
// prep: zero cnt + repack W1 (2048 frags) + FUSED att columns for layer 1
// (tiles ct=8 hi / ct=9 lo) + repack W2 (pad 40->48, fused as2/ad2 in pad
// cols 40..43). a_src = x @ (W1 @ att_src) comes straight out of MFMA.
// ---------------------------------------------------------------------------
__global__ __launch_bounds__(256) void k_prep(const float* __restrict__ W1,
                                              bf16x8* __restrict__ Wp,
                                              const float* __restrict__ W2,
                                              bf16x8* __restrict__ W2p,
                                              const float* __restrict__ att_s1,
                                              const float* __restrict__ att_d1,
                                              const float* __restrict__ att_s2,
                                              const float* __restrict__ att_d2,
                                              int* __restrict__ cnt, int N) {
    int g = blockIdx.x * 256 + threadIdx.x;
    if (g < 2048) {
        int n = g & 15, quad = (g >> 4) & 3, c = (g >> 6) & 3, ct = g >> 8;
        bf16x8 v;
#pragma unroll
        for (int j = 0; j < 8; ++j)
            v[j] = (__bf16)W1[(c * 32 + quad * 8 + j) * 128 + ct * 16 + n];
        Wp[g] = v;
    } else if (g < 2560) {
        // fused layer-1 attention tiles: ct=8 (hi), ct=9 (lo)
        int idx = g - 2048;
        int n = idx & 15, quad = (idx >> 4) & 3, c = (idx >> 6) & 3, t8 = idx >> 8;
        int h = n & 7;
        const float* av = (n < 8) ? att_s1 : att_d1;
        bf16x8 vv;
#pragma unroll
        for (int j = 0; j < 8; ++j) {
            int f = c * 32 + quad * 8 + j;
            float full = 0.f;
            for (int cc = 0; cc < 16; ++cc)
                full += W1[f * 128 + h * 16 + cc] * av[h * 16 + cc];
            __bf16 hi = (__bf16)full;
            vv[j] = t8 ? (__bf16)(full - (float)hi) : hi;
        }
        Wp[g] = vv;
    } else if (g < 3328) {
        int idx = g - 2560;
        int n = idx & 15, quad = (idx >> 4) & 3, c = (idx >> 6) & 3, ct = idx >> 8;
        int colc = ct * 16 + n;
        bf16x8 v;
        if (colc < 40) {
#pragma unroll
            for (int j = 0; j < 8; ++j)
                v[j] = (__bf16)W2[(c * 32 + quad * 8 + j) * 40 + colc];
        } else if (ct == 2 && n >= 8 && n < 12) {
            // fused layer-2 attention cols: 40=as hi, 41=ad hi, 42=as lo, 43=ad lo
            const float* av = (n & 1) ? att_d2 : att_s2;
#pragma unroll
            for (int j = 0; j < 8; ++j) {
                int f = c * 32 + quad * 8 + j;
                float full = 0.f;
                for (int cc = 0; cc < 40; ++cc) full += W2[f * 40 + cc] * av[cc];
                __bf16 hi = (__bf16)full;
                v[j] = (n >= 10) ? (__bf16)(full - (float)hi) : hi;
            }
        } else {
#pragma unroll
            for (int j = 0; j < 8; ++j) v[j] = (__bf16)0.f;
        }
        W2p[idx] = v;
    }
    if (g < N) cnt[g] = 0;
}

// ---------------------------------------------------------------------------
// histogram of dst (incl. self-loops); emits rank[e] (single atomic pass)
// ---------------------------------------------------------------------------
__global__ __launch_bounds__(256) void k_hist(const int* __restrict__ ei, int E, int N,
                                              int* __restrict__ cnt,
                                              unsigned short* __restrict__ rank) {
    int e = blockIdx.x * 256 + threadIdx.x;
    if (e >= E + N) return;
    int d = (e < E) ? ei[E + e] : (e - E);
    rank[e] = (unsigned short)atomicAdd(&cnt[d], 1);
}

// ---------------------------------------------------------------------------
// 2-stage exclusive scan of cnt[N] -> rowptr[N] (+ rowptr[N] sentinel).
// ---------------------------------------------------------------------------
__global__ __launch_bounds__(256) void k_scan_part(const int* __restrict__ cnt, int N,
                                                   int* __restrict__ psum) {
    __shared__ int sh[256];
    int t = threadIdx.x;
    int base = blockIdx.x * 1024 + t * 4;
    int tl = 0;
#pragma unroll
    for (int j = 0; j < 4; ++j) tl += (base + j < N) ? cnt[base + j] : 0;
    sh[t] = tl; __syncthreads();
    for (int off = 128; off > 0; off >>= 1) {
        if (t < off) sh[t] += sh[t + off];
        __syncthreads();
    }
    if (t == 0) psum[blockIdx.x] = sh[0];
}

__global__ __launch_bounds__(256) void k_scan_add(const int* __restrict__ cnt, int N,
                                                  const int* __restrict__ psum,
                                                  int* __restrict__ rowptr) {
    __shared__ int sh[256];
    __shared__ int basep;
    int t = threadIdx.x;
    if (t == 0) {
        int s = 0;
        for (int i = 0; i < blockIdx.x; ++i) s += psum[i];
        basep = s;
    }
    int base = blockIdx.x * 1024 + t * 4;
    int c[4]; int tl = 0;
#pragma unroll
    for (int j = 0; j < 4; ++j) { c[j] = (base + j < N) ? cnt[base + j] : 0; tl += c[j]; }
    sh[t] = tl; __syncthreads();
    for (int off = 1; off < 256; off <<= 1) {
        int a = (t >= off) ? sh[t - off] : 0;
        __syncthreads();
        sh[t] += a;
        __syncthreads();
    }
    int run = basep + (sh[t] - tl);
#pragma unroll
    for (int j = 0; j < 4; ++j) {
        if (base + j < N) {
            rowptr[base + j] = run; run += c[j];
            if (base + j == N - 1) rowptr[N] = run;   // sentinel for deg via deltas
        }
    }
}

// ---------------------------------------------------------------------------
// scatter src into CSR by dst using precomputed rank (no atomics); col ushort
// ---------------------------------------------------------------------------
__global__ __launch_bounds__(256) void k_scatter(const int* __restrict__ ei, int E, int N,
                                                 const int* __restrict__ rowptr,
                                                 const unsigned short* __restrict__ rank,
                                                 unsigned short* __restrict__ col) {
    int e = blockIdx.x * 256 + threadIdx.x;
    if (e >= E + N) return;
    int s, d;
    if (e < E) { s = ei[e]; d = ei[E + e]; } else { s = d = e - E; }
    col[rowptr[d] + (int)rank[e]] = (unsigned short)s;
}

// ---------------------------------------------------------------------------
// GEMM1 via MFMA: [N,128]@[128,160]: 8 output tiles + 2 fused attention
// tiles (hi/lo). h1 written CHANNEL-EIGHTH-MAJOR: h1E[ct][node][16]
// (each MFMA column-tile ct IS one eighth -- same stores, new layout) so
// aggr1 can gather from per-XCD-L2-resident 1.6 MB sub-tables.
// ---------------------------------------------------------------------------
__global__ __launch_bounds__(256) void k_gemm1(const float* __restrict__ x,
                                               const bf16x8* __restrict__ Wp,
                                               unsigned short* __restrict__ h1E,
                                               float* __restrict__ a_src,
                                               float* __restrict__ a_dst, int N, int NpU) {
    int t = threadIdx.x;
    int w = t >> 6, lane = t & 63, quad = lane >> 4, n16 = lane & 15;
    int row0 = blockIdx.x * 64 + w * 16;
    int arow = row0 + n16; if (arow >= N) arow = N - 1;
    const float* px = x + (size_t)arow * 128;

    bf16x8 ah[4], al[4];
#pragma unroll
    for (int c = 0; c < 4; ++c) {
        float4 v0 = *(const float4*)&px[c * 32 + quad * 8];
        float4 v1 = *(const float4*)&px[c * 32 + quad * 8 + 4];
        float xf[8] = {v0.x, v0.y, v0.z, v0.w, v1.x, v1.y, v1.z, v1.w};
#pragma unroll
        for (int j = 0; j < 8; ++j) {
            __bf16 hi = (__bf16)xf[j];
            ah[c][j] = hi;
            al[c][j] = (__bf16)(xf[j] - (float)hi);
        }
    }

    f32x4 acc[10];
#pragma unroll
    for (int ct = 0; ct < 10; ++ct) acc[ct] = (f32x4){0.f, 0.f, 0.f, 0.f};

    const uint4* wp4 = (const uint4*)Wp;
#pragma unroll
    for (int ct = 0; ct < 10; ++ct) {
#pragma unroll
        for (int c = 0; c < 4; ++c) {
            union { uint4 u; bf16x8 b; } bu;
            bu.u = wp4[((ct * 4 + c) * 4 + quad) * 16 + n16];
            acc[ct] = __builtin_amdgcn_mfma_f32_16x16x32_bf16(ah[c], bu.b, acc[ct], 0, 0, 0);
            acc[ct] = __builtin_amdgcn_mfma_f32_16x16x32_bf16(al[c], bu.b, acc[ct], 0, 0, 0);
        }
    }

    int nodeb = row0 + quad * 4;
#pragma unroll
    for (int ct = 0; ct < 8; ++ct) {
        unsigned short* hp = h1E + (size_t)ct * NpU * 16;
#pragma unroll
        for (int reg = 0; reg < 4; ++reg) {
            int node = nodeb + reg;
            if (node < N) hp[node * 16 + n16] = f2bfu(acc[ct][reg]);
        }
    }
#pragma unroll
    for (int reg = 0; reg < 4; ++reg) {
        int node = nodeb + reg;
        float av = acc[8][reg] + acc[9][reg];
        if (node < N) {
            if (n16 < 8) a_src[(size_t)node * 8 + n16] = av;
            else         a_dst[(size_t)node * 8 + (n16 - 8)] = av;
        }
    }
}

// ---------------------------------------------------------------------------
// Layer-1 aggregation, 8 CHANNEL-EIGHTH passes with XCD L2 affinity:
// p = blockIdx & 7 (== XCD on round-robin dispatch), so each XCD's blocks
// gather ONLY their 1.6 MB h1E[p] sub-table + a_src -> L2-resident.
// (Rounds 0-6 showed aggr1 pinned at 43-48 us / 97-99 MB FETCH regardless
// of VALU structure: bound by LLC->L2 fills, 6.4 MB working set vs 4 MiB
// per-XCD L2. This kills those fills.)
// Consumer SAFETY (R7 crash fix): loop bounds use each half's OWN ldeg --
// exec-mask handles divergent trip counts between halves; all colL indices
// provably <= wsz+30 < wsz+GZ (prologue <= ob+31 with ob <= wsz-1; body
// prefetch <= ob + own_ldeg + 14 <= wsz + 14). R7 used the pair-max bound
// with per-half ob -> OOB LDS -> garbage global gather -> fault.
// ---------------------------------------------------------------------------
__global__ __launch_bounds__(256) void k_aggr1(const int* __restrict__ rowptr,
                                               const unsigned short* __restrict__ col,
                                               const float* __restrict__ a_src,
                                               const float* __restrict__ a_dst,
                                               const unsigned int* __restrict__ h1E,
                                               const float* __restrict__ bias1,
                                               unsigned int* __restrict__ out1h,
                                               unsigned int* __restrict__ out1l,
                                               int N, int NpU) {
    __shared__ float evL[WSZ + GZ];
    __shared__ int   colL[WSZ + GZ];
    __shared__ int   rpL[9];
    __shared__ float adL[8];
    int p = blockIdx.x & 7;          // XCD-affine channel eighth
    int blk = blockIdx.x >> 3;
    const uint4* hp4 = (const uint4*)(h1E + (size_t)p * NpU * 8);
    int t = threadIdx.x;
    int node0 = blk * 8;
    if (t < 9) {
        int nd = node0 + t; if (nd > N) nd = N;
        rpL[t] = rowptr[nd];
    }
    if (t >= 64 && t < 72) {
        int nd = node0 + (t - 64); if (nd >= N) nd = N - 1;
        adL[t - 64] = a_dst[(size_t)nd * 8 + p];
    }
    __syncthreads();
    int w0v = rpL[0], end8 = rpL[8];

    int w = t >> 6, lane = t & 63, half = lane >> 5, u = lane & 31;
    int e16 = u >> 1, v = u & 1;     // 2 lanes per edge; lane v owns 8 ch (uint4)
    int idx8 = w * 2 + half;
    int node = node0 + idx8;
    bool nv = (node < N);
    int beg = rpL[idx8], end = rpL[idx8 + 1];

    float den = 0.f;
    float nm[8];
#pragma unroll
    for (int k = 0; k < 8; ++k) nm[k] = 0.f;

    for (int w0 = w0v; w0 < end8; w0 += WSZ) {
        int wend = w0 + WSZ; if (wend > end8) wend = end8;
        int wsz = wend - w0;
        if (w0 != w0v) __syncthreads();      // LDS reuse guard (rare 2nd window)
        // ---- fill: this eighth's head ----
        for (int s = w0 + t; s < wend; s += 256) {
            int su = (int)col[s];
            int lo2 = 0;
            if (rpL[lo2 + 4] <= s) lo2 += 4;
            if (rpL[lo2 + 2] <= s) lo2 += 2;
            if (rpL[lo2 + 1] <= s) lo2 += 1;
            evL[s - w0] = __expf(lrelu(a_src[(size_t)su * 8 + p] + adL[lo2]));
            colL[s - w0] = su;
        }
        if (t < GZ) {                        // guard zone: safe col + zero ev
            colL[wsz + t] = 0;
            evL[wsz + t] = 0.f;
        }
        __syncthreads();
        // ---- consumer: own-ldeg bounds (exec-mask divergence between halves) ----
        int lbeg = (beg > w0) ? beg : w0;
        int lend = (end < wend) ? end : wend;
        int ldeg = lend - lbeg;              // own degree in this window
        if (ldeg > 0) {
            int ob = lbeg - w0;              // in [0, wsz-1]
            int ng = (ldeg + 15) >> 4;       // 16-edge groups, own count
            int o1 = (ng > 1) ? 16 : 0;
            uint4 U0 = hp4[colL[ob + e16] * 2 + v];
            uint4 U1 = hp4[colL[ob + o1 + e16] * 2 + v];
            int body = ng - 2;
            int g = 0;
#pragma unroll 2
            for (; g < body; ++g) {
                uint4 UN = hp4[colL[ob + (g + 2) * 16 + e16] * 2 + v];
                int ii = g * 16 + e16;
                float ev = (ii < ldeg) ? evL[ob + ii] : 0.f;
                den += ev;
                nm[0] = fmaf(ev, bf_lo(U0.x), nm[0]);
                nm[1] = fmaf(ev, bf_hi(U0.x), nm[1]);
                nm[2] = fmaf(ev, bf_lo(U0.y), nm[2]);
                nm[3] = fmaf(ev, bf_hi(U0.y), nm[3]);
                nm[4] = fmaf(ev, bf_lo(U0.z), nm[4]);
                nm[5] = fmaf(ev, bf_hi(U0.z), nm[5]);
                nm[6] = fmaf(ev, bf_lo(U0.w), nm[6]);
                nm[7] = fmaf(ev, bf_hi(U0.w), nm[7]);
                U0 = U1; U1 = UN;
            }
            for (; g < ng; ++g) {            // drain: no loads
                int ii = g * 16 + e16;
                float ev = (ii < ldeg) ? evL[ob + ii] : 0.f;
                den += ev;
                nm[0] = fmaf(ev, bf_lo(U0.x), nm[0]);
                nm[1] = fmaf(ev, bf_hi(U0.x), nm[1]);
                nm[2] = fmaf(ev, bf_lo(U0.y), nm[2]);
                nm[3] = fmaf(ev, bf_hi(U0.y), nm[3]);
                nm[4] = fmaf(ev, bf_lo(U0.z), nm[4]);
                nm[5] = fmaf(ev, bf_hi(U0.z), nm[5]);
                nm[6] = fmaf(ev, bf_lo(U0.w), nm[6]);
                nm[7] = fmaf(ev, bf_hi(U0.w), nm[7]);
                U0 = U1;
            }
        }
    }
    // fold the 16 edge-subgroups (lanes sharing v and half: xor 2,4,8,16)
    den += __shfl_xor(den, 2);
    den += __shfl_xor(den, 4);
    den += __shfl_xor(den, 8);
    den += __shfl_xor(den, 16);
#pragma unroll
    for (int k = 0; k < 8; ++k) {
        float xv = nm[k];
        xv += __shfl_xor(xv, 2);
        xv += __shfl_xor(xv, 4);
        xv += __shfl_xor(xv, 8);
        xv += __shfl_xor(xv, 16);
        nm[k] = xv;
    }
    if (nv && u < 2) {                       // e16 == 0; lanes v=0,1 write 8 ch each
        float inv = 1.f / (den + 1e-16f);
        float4 b0 = *(const float4*)&bias1[p * 16 + v * 8];
        float4 b1 = *(const float4*)&bias1[p * 16 + v * 8 + 4];
        float bb[8] = {b0.x, b0.y, b0.z, b0.w, b1.x, b1.y, b1.z, b1.w};
        unsigned int H[4], L[4];
#pragma unroll
        for (int q = 0; q < 4; ++q) {
            float o0 = fmaf(nm[2 * q],     inv, bb[2 * q]);
            float o1 = fmaf(nm[2 * q + 1], inv, bb[2 * q + 1]);
            unsigned short h0 = f2bfu(o0), h1 = f2bfu(o1);
            float l0 = o0 - bfu2f(h0), l1 = o1 - bfu2f(h1);
            H[q] = (unsigned int)h0 | ((unsigned int)h1 << 16);
            L[q] = (unsigned int)f2bfu(l0) | ((unsigned int)f2bfu(l1) << 16);
        }
        size_t idx = (size_t)node * 64 + p * 8 + v * 4;
        *(uint4*)&out1h[idx] = make_uint4(H[0], H[1], H[2], H[3]);
        *(uint4*)&out1l[idx] = make_uint4(L[0], L[1], L[2], L[3]);
    }
}

// ---------------------------------------------------------------------------
// GEMM2 via MFMA: [N,128]@[128,48]; fused as2/ad2 in pad cols 40..43.
// ---------------------------------------------------------------------------
__global__ __launch_bounds__(256) void k_gemm2(const unsigned int* __restrict__ out1h,
                                               const unsigned int* __restrict__ out1l,
                                               const bf16x8* __restrict__ W2p,
                                               unsigned short* __restrict__ h2s,
                                               float* __restrict__ a_src2,
                                               float* __restrict__ a_dst2, int N) {
    int t = threadIdx.x;
    int w = t >> 6, lane = t & 63, quad = lane >> 4, n16 = lane & 15;
    int row0 = blockIdx.x * 64 + w * 16;
    int arow = row0 + n16; if (arow >= N) arow = N - 1;

    bf16x8 ah[4], al[4];
#pragma unroll
    for (int c = 0; c < 4; ++c) {
        size_t base = (size_t)arow * 64 + (c * 32 + quad * 8) / 2;
        union { uint4 u; bf16x8 b; } hu, lu;
        hu.u = *(const uint4*)&out1h[base];
        lu.u = *(const uint4*)&out1l[base];
        ah[c] = hu.b;
        al[c] = lu.b;
    }

    f32x4 acc[3];
#pragma unroll
    for (int ct = 0; ct < 3; ++ct) acc[ct] = (f32x4){0.f, 0.f, 0.f, 0.f};

    const uint4* wp4 = (const uint4*)W2p;
#pragma unroll
    for (int ct = 0; ct < 3; ++ct) {
#pragma unroll
        for (int c = 0; c < 4; ++c) {
            union { uint4 u; bf16x8 b; } bu;
            bu.u = wp4[((ct * 4 + c) * 4 + quad) * 16 + n16];
            acc[ct] = __builtin_amdgcn_mfma_f32_16x16x32_bf16(ah[c], bu.b, acc[ct], 0, 0, 0);
            acc[ct] = __builtin_amdgcn_mfma_f32_16x16x32_bf16(al[c], bu.b, acc[ct], 0, 0, 0);
        }
    }

    int nodeb = row0 + quad * 4;
#pragma unroll
    for (int reg = 0; reg < 4; ++reg) {
        int node = nodeb + reg;
#pragma unroll
        for (int ct = 0; ct < 3; ++ct) {
            int ch = ct * 16 + n16;
            if (node < N && ch < 40) h2s[(size_t)node * 64 + ch] = f2bfu(acc[ct][reg]);
        }
        float fv = acc[2][reg];
        float fused = fv + __shfl_xor(fv, 2);   // lane 8+10 (as hi+lo), 9+11 (ad)
        if (node < N) {
            if (n16 == 8) a_src2[node] = fused;
            else if (n16 == 9) a_dst2[node] = fused;
        }
    }
}

// ---------------------------------------------------------------------------
// Layer-2 aggregation: fused block-cooperative ev fill (scalar) + guard-zone
// padded x4 consumer (per-chunk own-degree guard -- proven safe since R4).
// Final output write. (Unchanged -- isolating the aggr1 XCD mechanism.)
// ---------------------------------------------------------------------------
__global__ __launch_bounds__(256) void k_aggr2(const int* __restrict__ rowptr,
                                               const unsigned short* __restrict__ col,
                                               const float* __restrict__ a_src2,
                                               const float* __restrict__ a_dst2,
                                               const unsigned int* __restrict__ h2b,
                                               const float* __restrict__ bias2,
                                               float* __restrict__ out, int N) {
    __shared__ float evL[WSZ + GZ];
    __shared__ int   colL[WSZ + GZ];
    __shared__ int   rpL[9];
    __shared__ float adL[8];
    int t = threadIdx.x;
    int node0 = blockIdx.x * 8;
    if (t < 9) {
        int nd = node0 + t; if (nd > N) nd = N;
        rpL[t] = rowptr[nd];
    }
    if (t >= 64 && t < 72) {
        int nd = node0 + (t - 64); if (nd >= N) nd = N - 1;
        adL[t - 64] = a_dst2[nd];
    }
    __syncthreads();
    int w0v = rpL[0], end8 = rpL[8];

    int w = t >> 6, lane = t & 63, half = lane >> 5, u = lane & 31;
    int e4 = u >> 3, v = u & 7;
    int idx8 = w * 2 + half;
    int node = node0 + idx8;
    bool nv = (node < N);
    int beg = rpL[idx8], end = rpL[idx8 + 1];

    const uint4* h24 = (const uint4*)h2b;
    float den = 0.f;
    float am[8];
#pragma unroll
    for (int k = 0; k < 8; ++k) am[k] = 0.f;

    for (int w0 = w0v; w0 < end8; w0 += WSZ) {
        int wend = w0 + WSZ; if (wend > end8) wend = end8;
        int wsz = wend - w0;
        if (w0 != w0v) __syncthreads();
        for (int s = w0 + t; s < wend; s += 256) {
            int su = (int)col[s];
            int lo2 = 0;
            if (rpL[lo2 + 4] <= s) lo2 += 4;
            if (rpL[lo2 + 2] <= s) lo2 += 2;
            if (rpL[lo2 + 1] <= s) lo2 += 1;
            evL[s - w0] = __expf(lrelu(a_src2[su] + adL[lo2]));
            colL[s - w0] = su;
        }
        if (t < GZ) {
            colL[wsz + t] = 0;
            evL[wsz + t] = 0.f;
        }
        __syncthreads();
        int lbeg = (beg > w0) ? beg : w0;
        int lend = (end < wend) ? end : wend;
        int ldeg = lend - lbeg;
        int ldO = __shfl_xor(ldeg, 32);
        int ldm = (ldeg > ldO) ? ldeg : ldO;
        int ob0 = lbeg - w0;
        for (int c = 0; c < ldm; c += 32) {
            int ccm = ldeg - c;
            if (ccm <= 0) continue;
            if (ccm > 32) ccm = 32;
            int ng = (ccm + 3) >> 2;
            int ob = ob0 + c;
            uint4 U0 = h24[colL[ob + e4] * 8 + v];
            uint4 U1 = h24[colL[ob + 4 + e4] * 8 + v];
            uint4 U2 = h24[colL[ob + 8 + e4] * 8 + v];
            uint4 U3 = h24[colL[ob + 12 + e4] * 8 + v];
            int body = ng - 4;
            int g = 0;
#pragma unroll 2
            for (; g < body; ++g) {
                uint4 UN = h24[colL[ob + (g + 4) * 4 + e4] * 8 + v];
                int ii = g * 4 + e4;
                float evv = (c + ii < ldeg) ? evL[ob + ii] : 0.f;
                den += evv;
                am[0] = fmaf(evv, bf_lo(U0.x), am[0]);
                am[1] = fmaf(evv, bf_hi(U0.x), am[1]);
                am[2] = fmaf(evv, bf_lo(U0.y), am[2]);
                am[3] = fmaf(evv, bf_hi(U0.y), am[3]);
                am[4] = fmaf(evv, bf_lo(U0.z), am[4]);
                am[5] = fmaf(evv, bf_hi(U0.z), am[5]);
                am[6] = fmaf(evv, bf_lo(U0.w), am[6]);
                am[7] = fmaf(evv, bf_hi(U0.w), am[7]);
                U0 = U1; U1 = U2; U2 = U3; U3 = UN;
            }
            for (; g < ng; ++g) {
                int ii = g * 4 + e4;
                float evv = (c + ii < ldeg) ? evL[ob + ii] : 0.f;
                den += evv;
                am[0] = fmaf(evv, bf_lo(U0.x), am[0]);
                am[1] = fmaf(evv, bf_hi(U0.x), am[1]);
                am[2] = fmaf(evv, bf_lo(U0.y), am[2]);
                am[3] = fmaf(evv, bf_hi(U0.y), am[3]);
                am[4] = fmaf(evv, bf_lo(U0.z), am[4]);
                am[5] = fmaf(evv, bf_hi(U0.z), am[5]);
                am[6] = fmaf(evv, bf_lo(U0.w), am[6]);
                am[7] = fmaf(evv, bf_hi(U0.w), am[7]);
                U0 = U1; U1 = U2; U2 = U3;
            }
        }
    }
    den += __shfl_xor(den, 8);
    den += __shfl_xor(den, 16);
#pragma unroll
    for (int k = 0; k < 8; ++k) {
        am[k] += __shfl_xor(am[k], 8);
        am[k] += __shfl_xor(am[k], 16);
    }
    if (nv && e4 == 0 && v < 5) {
        float inv = 1.f / (den + 1e-16f);
        float4 b0 = *(const float4*)&bias2[v * 8];
        float4 b1 = *(const float4*)&bias2[v * 8 + 4];
        float4 o0 = make_float4(fmaf(am[0], inv, b0.x), fmaf(am[1], inv, b0.y),
                                fmaf(am[2], inv, b0.z), fmaf(am[3], inv, b0.w));
        float4 o1 = make_float4(fmaf(am[4], inv, b1.x), fmaf(am[5], inv, b1.y),
                                fmaf(am[6], inv, b1.z), fmaf(am[7], inv, b1.w));
        size_t ob = (size_t)node * 40 + v * 8;
        *(float4*)&out[ob] = o0;
        *(float4*)&out[ob + 4] = o1;
    }
}

// ---------------------------------------------------------------------------
extern "C" void kernel_launch(void* const* d_in, const int* in_sizes, int n_in,
                              void* d_out, int out_size, void* d_ws, size_t ws_size,
                              hipStream_t stream) {
    const float* x   = (const float*)d_in[0];
    const int*   ei  = (const int*)d_in[1];
    const float* W1  = (const float*)d_in[2];
    const float* as1 = (const float*)d_in[3];
    const float* ad1 = (const float*)d_in[4];
    const float* b1  = (const float*)d_in[5];
    const float* W2  = (const float*)d_in[6];
    const float* as2 = (const float*)d_in[7];
    const float* ad2 = (const float*)d_in[8];
    const float* b2  = (const float*)d_in[9];

    int N = in_sizes[0] / 128;
    int E = in_sizes[1] / 2;
    int EN = E + N;
    size_t Np = (size_t)((N + 3) & ~3);
    size_t ENp = ((size_t)EN + 3) & ~3;

    float* ws = (float*)d_ws;
    unsigned int* out1h = (unsigned int*)ws; ws += Np * 64;  // hi bf16 pairs
    unsigned int* out1l = (unsigned int*)ws; ws += Np * 64;  // lo bf16 pairs
    unsigned int* h1E = (unsigned int*)ws; ws += Np * 64;    // 8 x [Np][16] bf16 eighths
    unsigned int* h2b = (unsigned int*)ws; ws += Np * 32;    // padded 128 B rows
    float* a_src1  = ws; ws += Np * 8;
    float* a_dst1  = ws; ws += Np * 8;
    float* a_src2v = ws; ws += Np;
    float* a_dst2v = ws; ws += Np;
    bf16x8* Wp  = (bf16x8*)ws; ws += 2560 * 4;               // 40 KB repacked W1 + fused att
    bf16x8* W2p = (bf16x8*)ws; ws += 768 * 4;                // 12 KB repacked W2 (+fused)
    int* cnt    = (int*)ws; ws += Np;
    int* rowptr = (int*)ws; ws += Np + 4;                    // +sentinel rowptr[N]
    int* psum   = (int*)ws; ws += 256;
    unsigned short* col  = (unsigned short*)ws; ws += ENp / 2 + 4;
    unsigned short* rank = (unsigned short*)ws; ws += ENp / 2 + 4;

    int nb = (N + 1023) / 1024;  // scan blocks (<=256)
    int npre = (N > 3328 ? N : 3328);

    k_prep<<<(npre + 255) / 256, 256, 0, stream>>>(W1, Wp, W2, W2p,
                                                   as1, ad1, as2, ad2, cnt, N);
    k_gemm1<<<(N + 63) / 64, 256, 0, stream>>>(x, Wp, (unsigned short*)h1E,
                                               a_src1, a_dst1, N, (int)Np);
    k_hist<<<(EN + 255) / 256, 256, 0, stream>>>(ei, E, N, cnt, rank);
    k_scan_part<<<nb, 256, 0, stream>>>(cnt, N, psum);
    k_scan_add<<<nb, 256, 0, stream>>>(cnt, N, psum, rowptr);
    k_scatter<<<(EN + 255) / 256, 256, 0, stream>>>(ei, E, N, rowptr, rank, col);

    int nag = (N + 7) / 8;
    k_aggr1<<<8 * nag, 256, 0, stream>>>(rowptr, col, a_src1, a_dst1,
                                         h1E, b1, out1h, out1l, N, (int)Np);
    k_gemm2<<<(N + 63) / 64, 256, 0, stream>>>(out1h, out1l, W2p,
                                               (unsigned short*)h2b, a_src2v, a_dst2v, N);
    k_aggr2<<<nag, 256, 0, stream>>>(rowptr, col, a_src2v, a_dst2v, h2b, b2, (float*)d_out, N);
}

// Round 9
// 232.798 us; speedup vs baseline: 1.2867x; 1.2867x over previous
//
#include <hip/hip_runtime.h>
#include <hip/hip_bf16.h>
#include <math.h>

#define NEG_SLOPE 0.2f

typedef __bf16 bf16x8 __attribute__((ext_vector_type(8)));
typedef float f32x4 __attribute__((ext_vector_type(4)));

__device__ __forceinline__ float lrelu(float x) { return x > 0.f ? x : NEG_SLOPE * x; }

__device__ __forceinline__ unsigned short f2bfu(float f) {
    unsigned int ua = __float_as_uint(f);
    return (unsigned short)((ua + 0x7fffu + ((ua >> 16) & 1u)) >> 16);
}
__device__ __forceinline__ float bfu2f(unsigned short u) {
    return __uint_as_float(((unsigned int)u) << 16);
}
__device__ __forceinline__ float bf_lo(unsigned int u) { return __uint_as_float(u << 16); }
__device__ __forceinline__ float bf_hi(unsigned int u) { return __uint_as_float(u & 0xffff0000u); }

// ---------------------------------------------------------------------------
// prep: zero cnt + repack W1 (2048 frags) + FUSED att columns for layer 1
// (tiles ct=8 hi / ct=9 lo) + repack W2 (pad 40->48, fused as2/ad2 in pad
// cols 40..43). a_src = x @ (W1 @ att_src) comes straight out of MFMA.
// (Verified R4-R6, absmax identical to shuffle path.)
// ---------------------------------------------------------------------------
__global__ __launch_bounds__(256) void k_prep(const float* __restrict__ W1,
                                              bf16x8* __restrict__ Wp,
                                              const float* __restrict__ W2,
                                              bf16x8* __restrict__ W2p,
                                              const float* __restrict__ att_s1,
                                              const float* __restrict__ att_d1,
                                              const float* __restrict__ att_s2,
                                              const float* __restrict__ att_d2,
                                              int* __restrict__ cnt, int N) {
    int g = blockIdx.x * 256 + threadIdx.x;
    if (g < 2048) {
        int n = g & 15, quad = (g >> 4) & 3, c = (g >> 6) & 3, ct = g >> 8;
        bf16x8 v;
#pragma unroll
        for (int j = 0; j < 8; ++j)
            v[j] = (__bf16)W1[(c * 32 + quad * 8 + j) * 128 + ct * 16 + n];
        Wp[g] = v;
    } else if (g < 2560) {
        // fused layer-1 attention tiles: ct=8 (hi), ct=9 (lo)
        int idx = g - 2048;
        int n = idx & 15, quad = (idx >> 4) & 3, c = (idx >> 6) & 3, t8 = idx >> 8;
        int h = n & 7;
        const float* av = (n < 8) ? att_s1 : att_d1;
        bf16x8 vv;
#pragma unroll
        for (int j = 0; j < 8; ++j) {
            int f = c * 32 + quad * 8 + j;
            float full = 0.f;
            for (int cc = 0; cc < 16; ++cc)
                full += W1[f * 128 + h * 16 + cc] * av[h * 16 + cc];
            __bf16 hi = (__bf16)full;
            vv[j] = t8 ? (__bf16)(full - (float)hi) : hi;
        }
        Wp[g] = vv;
    } else if (g < 3328) {
        int idx = g - 2560;
        int n = idx & 15, quad = (idx >> 4) & 3, c = (idx >> 6) & 3, ct = idx >> 8;
        int colc = ct * 16 + n;
        bf16x8 v;
        if (colc < 40) {
#pragma unroll
            for (int j = 0; j < 8; ++j)
                v[j] = (__bf16)W2[(c * 32 + quad * 8 + j) * 40 + colc];
        } else if (ct == 2 && n >= 8 && n < 12) {
            // fused layer-2 attention cols: 40=as hi, 41=ad hi, 42=as lo, 43=ad lo
            const float* av = (n & 1) ? att_d2 : att_s2;
#pragma unroll
            for (int j = 0; j < 8; ++j) {
                int f = c * 32 + quad * 8 + j;
                float full = 0.f;
                for (int cc = 0; cc < 40; ++cc) full += W2[f * 40 + cc] * av[cc];
                __bf16 hi = (__bf16)full;
                v[j] = (n >= 10) ? (__bf16)(full - (float)hi) : hi;
            }
        } else {
#pragma unroll
            for (int j = 0; j < 8; ++j) v[j] = (__bf16)0.f;
        }
        W2p[idx] = v;
    }
    if (g < N) cnt[g] = 0;
}

// ---------------------------------------------------------------------------
// histogram of dst (incl. self-loops); emits rank[e] (single atomic pass)
// ---------------------------------------------------------------------------
__global__ __launch_bounds__(256) void k_hist(const int* __restrict__ ei, int E, int N,
                                              int* __restrict__ cnt,
                                              unsigned short* __restrict__ rank) {
    int e = blockIdx.x * 256 + threadIdx.x;
    if (e >= E + N) return;
    int d = (e < E) ? ei[E + e] : (e - E);
    rank[e] = (unsigned short)atomicAdd(&cnt[d], 1);
}

// ---------------------------------------------------------------------------
// 2-stage exclusive scan of cnt[N] -> rowptr[N].
// ---------------------------------------------------------------------------
__global__ __launch_bounds__(256) void k_scan_part(const int* __restrict__ cnt, int N,
                                                   int* __restrict__ psum) {
    __shared__ int sh[256];
    int t = threadIdx.x;
    int base = blockIdx.x * 1024 + t * 4;
    int tl = 0;
#pragma unroll
    for (int j = 0; j < 4; ++j) tl += (base + j < N) ? cnt[base + j] : 0;
    sh[t] = tl; __syncthreads();
    for (int off = 128; off > 0; off >>= 1) {
        if (t < off) sh[t] += sh[t + off];
        __syncthreads();
    }
    if (t == 0) psum[blockIdx.x] = sh[0];
}

__global__ __launch_bounds__(256) void k_scan_add(const int* __restrict__ cnt, int N,
                                                  const int* __restrict__ psum,
                                                  int* __restrict__ rowptr) {
    __shared__ int sh[256];
    __shared__ int basep;
    int t = threadIdx.x;
    if (t == 0) {
        int s = 0;
        for (int i = 0; i < blockIdx.x; ++i) s += psum[i];
        basep = s;
    }
    int base = blockIdx.x * 1024 + t * 4;
    int c[4]; int tl = 0;
#pragma unroll
    for (int j = 0; j < 4; ++j) { c[j] = (base + j < N) ? cnt[base + j] : 0; tl += c[j]; }
    sh[t] = tl; __syncthreads();
    for (int off = 1; off < 256; off <<= 1) {
        int a = (t >= off) ? sh[t - off] : 0;
        __syncthreads();
        sh[t] += a;
        __syncthreads();
    }
    int run = basep + (sh[t] - tl);
#pragma unroll
    for (int j = 0; j < 4; ++j) {
        if (base + j < N) { rowptr[base + j] = run; run += c[j]; }
    }
}

// ---------------------------------------------------------------------------
// scatter src into CSR by dst using precomputed rank (no atomics); col ushort
// ---------------------------------------------------------------------------
__global__ __launch_bounds__(256) void k_scatter(const int* __restrict__ ei, int E, int N,
                                                 const int* __restrict__ rowptr,
                                                 const unsigned short* __restrict__ rank,
                                                 unsigned short* __restrict__ col) {
    int e = blockIdx.x * 256 + threadIdx.x;
    if (e >= E + N) return;
    int s, d;
    if (e < E) { s = ei[e]; d = ei[E + e]; } else { s = d = e - E; }
    col[rowptr[d] + (int)rank[e]] = (unsigned short)s;
}

// ---------------------------------------------------------------------------
// GEMM1 via MFMA: [N,128]@[128,160]: 8 output tiles + 2 fused attention
// tiles (hi/lo). Channel-split packed-bf16 h1A/h1B (128 B rows) out;
// a_src/a_dst straight from acc[8]+acc[9] -- no shuffle epilogue. (R3 form.)
// ---------------------------------------------------------------------------
__global__ __launch_bounds__(256) void k_gemm1(const float* __restrict__ x,
                                               const bf16x8* __restrict__ Wp,
                                               unsigned short* __restrict__ h1A,
                                               unsigned short* __restrict__ h1B,
                                               float* __restrict__ a_src,
                                               float* __restrict__ a_dst, int N) {
    int t = threadIdx.x;
    int w = t >> 6, lane = t & 63, quad = lane >> 4, n16 = lane & 15;
    int row0 = blockIdx.x * 64 + w * 16;
    int arow = row0 + n16; if (arow >= N) arow = N - 1;
    const float* px = x + (size_t)arow * 128;

    bf16x8 ah[4], al[4];
#pragma unroll
    for (int c = 0; c < 4; ++c) {
        float4 v0 = *(const float4*)&px[c * 32 + quad * 8];
        float4 v1 = *(const float4*)&px[c * 32 + quad * 8 + 4];
        float xf[8] = {v0.x, v0.y, v0.z, v0.w, v1.x, v1.y, v1.z, v1.w};
#pragma unroll
        for (int j = 0; j < 8; ++j) {
            __bf16 hi = (__bf16)xf[j];
            ah[c][j] = hi;
            al[c][j] = (__bf16)(xf[j] - (float)hi);
        }
    }

    f32x4 acc[10];
#pragma unroll
    for (int ct = 0; ct < 10; ++ct) acc[ct] = (f32x4){0.f, 0.f, 0.f, 0.f};

    const uint4* wp4 = (const uint4*)Wp;
#pragma unroll
    for (int ct = 0; ct < 10; ++ct) {
#pragma unroll
        for (int c = 0; c < 4; ++c) {
            union { uint4 u; bf16x8 b; } bu;
            bu.u = wp4[((ct * 4 + c) * 4 + quad) * 16 + n16];
            acc[ct] = __builtin_amdgcn_mfma_f32_16x16x32_bf16(ah[c], bu.b, acc[ct], 0, 0, 0);
            acc[ct] = __builtin_amdgcn_mfma_f32_16x16x32_bf16(al[c], bu.b, acc[ct], 0, 0, 0);
        }
    }

    int nodeb = row0 + quad * 4;
#pragma unroll
    for (int ct = 0; ct < 8; ++ct) {
        unsigned short* hp = (ct < 4) ? h1A : h1B;
        int chl = (ct & 3) * 16 + n16;
#pragma unroll
        for (int reg = 0; reg < 4; ++reg) {
            int node = nodeb + reg;
            if (node < N) hp[(size_t)node * 64 + chl] = f2bfu(acc[ct][reg]);
        }
    }
#pragma unroll
    for (int reg = 0; reg < 4; ++reg) {
        int node = nodeb + reg;
        float av = acc[8][reg] + acc[9][reg];
        if (node < N) {
            if (n16 < 8) a_src[(size_t)node * 8 + n16] = av;
            else         a_dst[(size_t)node * 8 + (n16 - 8)] = av;
        }
    }
}

// ---------------------------------------------------------------------------
// Layer-1 aggregation: ROUND-0 STRUCTURE (measured best, 43.4 us; every
// later restructuring measured 44-117). Blocks [0,nag) do p=0, [nag,2*nag)
// p=1. Two nodes per wave (32 lanes); lane u owns channels p*64+2u,2u+1.
// Per 32-edge chunk lane u computes 4 evs for edge u into per-wave LDS
// strips (wave-synchronous). Depth-3 prefetch with unclamped unrolled body
// + load-free 3-iter drain tail.
// ---------------------------------------------------------------------------
__global__ __launch_bounds__(256) void k_aggr1(const int* __restrict__ rowptr,
                                               const int* __restrict__ cnt,
                                               const unsigned short* __restrict__ col,
                                               const float* __restrict__ a_src,
                                               const float* __restrict__ a_dst,
                                               const unsigned int* __restrict__ h1A,
                                               const unsigned int* __restrict__ h1B,
                                               const float* __restrict__ bias1,
                                               unsigned int* __restrict__ out1h,
                                               unsigned int* __restrict__ out1l,
                                               int N, int nag) {
    __shared__ float evs[4][2][128];   // [wave][half][edge*4+head]
    __shared__ int   cls[4][2][32];    // [wave][half][edge]
    int p = (blockIdx.x >= nag) ? 1 : 0;
    int blk = blockIdx.x - p * nag;
    const unsigned int* hp = p ? h1B : h1A;
    int t = threadIdx.x;
    int w = t >> 6;
    int lane = t & 63;
    int half = lane >> 5;
    int u = lane & 31;
    int node = blk * 8 + w * 2 + half;
    bool nv = (node < N);
    int nodec = nv ? node : (N - 1);
    int beg = rowptr[nodec];
    int deg = nv ? cnt[nodec] : 0;
    int degO = __shfl_xor(deg, 32);
    int degmax = (deg > degO) ? deg : degO;
    if (degmax <= 0) return;   // uniform across wave

    int hh = u >> 3;                           // phase-local head 0..3
    float4 ad4 = *(const float4*)&a_dst[(size_t)nodec * 8 + p * 4];

    float* myev = &evs[w][half][0];
    int*   mycl = &cls[w][half][0];

    float den = 0.f, n0 = 0.f, n1 = 0.f;
    int c = 0;
    while (c < degmax) {
        int slot = c + u;
        int slotc = (slot < deg) ? slot : (deg - 1);
        if (slotc < 0) slotc = 0;
        int su = (int)col[beg + slotc];
        float4 as4 = *(const float4*)&a_src[(size_t)su * 8 + p * 4];
        bool valid = (slot < deg);
        float e0 = valid ? __expf(lrelu(as4.x + ad4.x)) : 0.f;
        float e1 = valid ? __expf(lrelu(as4.y + ad4.y)) : 0.f;
        float e2 = valid ? __expf(lrelu(as4.z + ad4.z)) : 0.f;
        float e3 = valid ? __expf(lrelu(as4.w + ad4.w)) : 0.f;
        *(float4*)&myev[u * 4] = make_float4(e0, e1, e2, e3);
        mycl[u] = su;
        // wave-synchronous LDS: single-wave producer/consumer, no barrier

        int ccm = degmax - c; ccm = (ccm < 32) ? ccm : 32;
        int last = ccm - 1;
        // depth-3 pipeline prologue (clamped)
        int s0 = mycl[0];
        unsigned int u0 = hp[s0 * 32 + u];
        int i1 = (1 < last) ? 1 : last;
        int s1 = mycl[i1];
        unsigned int u1 = hp[s1 * 32 + u];
        int i2 = (2 < last) ? 2 : last;
        int s2 = mycl[i2];
        unsigned int u2 = hp[s2 * 32 + u];
        int body = ccm - 3;
        int i = 0;
#pragma unroll 4
        for (; i < body; ++i) {
            int sN = mycl[i + 3];                // unclamped: i+3 <= last
            unsigned int uN = hp[sN * 32 + u];
            float ev = myev[i * 4 + hh];
            den += ev;
            n0 = fmaf(ev, bf_lo(u0), n0);
            n1 = fmaf(ev, bf_hi(u0), n1);
            u0 = u1; u1 = u2; u2 = uN;
        }
        for (; i < ccm; ++i) {                   // drain: no loads
            float ev = myev[i * 4 + hh];
            den += ev;
            n0 = fmaf(ev, bf_lo(u0), n0);
            n1 = fmaf(ev, bf_hi(u0), n1);
            u0 = u1; u1 = u2;
        }
        c += 32;
    }
    if (nv) {
        float inv = 1.f / (den + 1e-16f);
        int ch = p * 64 + 2 * u;
        float2 b = *(const float2*)&bias1[ch];
        float o0 = fmaf(n0, inv, b.x), o1 = fmaf(n1, inv, b.y);
        unsigned short h0 = f2bfu(o0), h1 = f2bfu(o1);
        float l0 = o0 - bfu2f(h0), l1 = o1 - bfu2f(h1);
        size_t idx = (size_t)node * 64 + p * 32 + u;
        out1h[idx] = (unsigned int)h0 | ((unsigned int)h1 << 16);
        out1l[idx] = (unsigned int)f2bfu(l0) | ((unsigned int)f2bfu(l1) << 16);
    }
}

// ---------------------------------------------------------------------------
// GEMM2 via MFMA: [N,128]@[128,48]; fused as2/ad2 in pad cols 40..43:
// a_src2/a_dst2 from acc[2] lanes 8/9 + 10/11 via one shfl_xor. (R3 form.)
// ---------------------------------------------------------------------------
__global__ __launch_bounds__(256) void k_gemm2(const unsigned int* __restrict__ out1h,
                                               const unsigned int* __restrict__ out1l,
                                               const bf16x8* __restrict__ W2p,
                                               unsigned short* __restrict__ h2s,
                                               float* __restrict__ a_src2,
                                               float* __restrict__ a_dst2, int N) {
    int t = threadIdx.x;
    int w = t >> 6, lane = t & 63, quad = lane >> 4, n16 = lane & 15;
    int row0 = blockIdx.x * 64 + w * 16;
    int arow = row0 + n16; if (arow >= N) arow = N - 1;

    bf16x8 ah[4], al[4];
#pragma unroll
    for (int c = 0; c < 4; ++c) {
        size_t base = (size_t)arow * 64 + (c * 32 + quad * 8) / 2;
        union { uint4 u; bf16x8 b; } hu, lu;
        hu.u = *(const uint4*)&out1h[base];
        lu.u = *(const uint4*)&out1l[base];
        ah[c] = hu.b;
        al[c] = lu.b;
    }

    f32x4 acc[3];
#pragma unroll
    for (int ct = 0; ct < 3; ++ct) acc[ct] = (f32x4){0.f, 0.f, 0.f, 0.f};

    const uint4* wp4 = (const uint4*)W2p;
#pragma unroll
    for (int ct = 0; ct < 3; ++ct) {
#pragma unroll
        for (int c = 0; c < 4; ++c) {
            union { uint4 u; bf16x8 b; } bu;
            bu.u = wp4[((ct * 4 + c) * 4 + quad) * 16 + n16];
            acc[ct] = __builtin_amdgcn_mfma_f32_16x16x32_bf16(ah[c], bu.b, acc[ct], 0, 0, 0);
            acc[ct] = __builtin_amdgcn_mfma_f32_16x16x32_bf16(al[c], bu.b, acc[ct], 0, 0, 0);
        }
    }

    int nodeb = row0 + quad * 4;
#pragma unroll
    for (int reg = 0; reg < 4; ++reg) {
        int node = nodeb + reg;
#pragma unroll
        for (int ct = 0; ct < 3; ++ct) {
            int ch = ct * 16 + n16;
            if (node < N && ch < 40) h2s[(size_t)node * 64 + ch] = f2bfu(acc[ct][reg]);
        }
        float fv = acc[2][reg];
        float fused = fv + __shfl_xor(fv, 2);   // lane 8+10 (as hi+lo), 9+11 (ad)
        if (node < N) {
            if (n16 == 8) a_src2[node] = fused;
            else if (n16 == 9) a_dst2[node] = fused;
        }
    }
}

// ---------------------------------------------------------------------------
// Layer-2 aggregation: ROUND-1 x4 STRUCTURE (isolated gain ~ -9 us vs x1):
// serial producer (col -> a_src gather -> expf inline); consumer 8 lanes per
// edge via dwordx4 (lane v -> ch 8v..8v+7; v>=5 hits pad uints, accumulates
// garbage never reduced into v<5 lanes nor written out), 4 edges/iter per
// 32-lane half, depth-4 uint4 rotation, load-free drain. Final output.
// ---------------------------------------------------------------------------
__global__ __launch_bounds__(256) void k_aggr2(const int* __restrict__ rowptr,
                                               const int* __restrict__ cnt,
                                               const unsigned short* __restrict__ col,
                                               const float* __restrict__ a_src,
                                               const float* __restrict__ a_dst,
                                               const unsigned int* __restrict__ h2b,
                                               const float* __restrict__ bias2,
                                               float* __restrict__ out, int N) {
    __shared__ float evs[4][2][32];
    __shared__ int   cls[4][2][32];
    int t = threadIdx.x;
    int w = t >> 6;
    int lane = t & 63;
    int half = lane >> 5;
    int u = lane & 31;
    int e4 = u >> 3;
    int v  = u & 7;
    int node = blockIdx.x * 8 + w * 2 + half;
    bool nv = (node < N);
    int nodec = nv ? node : (N - 1);
    int beg = rowptr[nodec];
    int deg = nv ? cnt[nodec] : 0;
    int degO = __shfl_xor(deg, 32);
    int degmax = (deg > degO) ? deg : degO;
    if (degmax <= 0) return;

    const uint4* h24 = (const uint4*)h2b;
    float ad = a_dst[nodec];
    float* myev = &evs[w][half][0];
    int*   mycl = &cls[w][half][0];

    float den = 0.f;
    float am[8];
#pragma unroll
    for (int k = 0; k < 8; ++k) am[k] = 0.f;

    int c = 0;
    while (c < degmax) {
        int slot = c + u;
        int slotc = (slot < deg) ? slot : (deg - 1);
        if (slotc < 0) slotc = 0;
        int su = (int)col[beg + slotc];
        float ev = (slot < deg) ? __expf(lrelu(a_src[su] + ad)) : 0.f;
        myev[u] = ev;
        mycl[u] = su;

        int ccm = degmax - c; ccm = (ccm < 32) ? ccm : 32;
        int ng = (ccm + 3) >> 2;
        int gl = ng - 1;
        int g1 = (1 < gl) ? 1 : gl;
        int g2 = (2 < gl) ? 2 : gl;
        int g3 = (3 < gl) ? 3 : gl;
        uint4 U0 = h24[mycl[e4] * 8 + v];
        uint4 U1 = h24[mycl[g1 * 4 + e4] * 8 + v];
        uint4 U2 = h24[mycl[g2 * 4 + e4] * 8 + v];
        uint4 U3 = h24[mycl[g3 * 4 + e4] * 8 + v];
        int body = ng - 4;
        int g = 0;
#pragma unroll 2
        for (; g < body; ++g) {
            uint4 UN = h24[mycl[(g + 4) * 4 + e4] * 8 + v];
            float evv = myev[g * 4 + e4];
            den += evv;
            am[0] = fmaf(evv, bf_lo(U0.x), am[0]);
            am[1] = fmaf(evv, bf_hi(U0.x), am[1]);
            am[2] = fmaf(evv, bf_lo(U0.y), am[2]);
            am[3] = fmaf(evv, bf_hi(U0.y), am[3]);
            am[4] = fmaf(evv, bf_lo(U0.z), am[4]);
            am[5] = fmaf(evv, bf_hi(U0.z), am[5]);
            am[6] = fmaf(evv, bf_lo(U0.w), am[6]);
            am[7] = fmaf(evv, bf_hi(U0.w), am[7]);
            U0 = U1; U1 = U2; U2 = U3; U3 = UN;
        }
        for (; g < ng; ++g) {
            float evv = myev[g * 4 + e4];
            den += evv;
            am[0] = fmaf(evv, bf_lo(U0.x), am[0]);
            am[1] = fmaf(evv, bf_hi(U0.x), am[1]);
            am[2] = fmaf(evv, bf_lo(U0.y), am[2]);
            am[3] = fmaf(evv, bf_hi(U0.y), am[3]);
            am[4] = fmaf(evv, bf_lo(U0.z), am[4]);
            am[5] = fmaf(evv, bf_hi(U0.z), am[5]);
            am[6] = fmaf(evv, bf_lo(U0.w), am[6]);
            am[7] = fmaf(evv, bf_hi(U0.w), am[7]);
            U0 = U1; U1 = U2; U2 = U3;
        }
        c += 32;
    }
    den += __shfl_xor(den, 8);
    den += __shfl_xor(den, 16);
#pragma unroll
    for (int k = 0; k < 8; ++k) {
        am[k] += __shfl_xor(am[k], 8);
        am[k] += __shfl_xor(am[k], 16);
    }
    if (nv && e4 == 0 && v < 5) {
        float inv = 1.f / (den + 1e-16f);
        float4 b0 = *(const float4*)&bias2[v * 8];
        float4 b1 = *(const float4*)&bias2[v * 8 + 4];
        float4 o0 = make_float4(fmaf(am[0], inv, b0.x), fmaf(am[1], inv, b0.y),
                                fmaf(am[2], inv, b0.z), fmaf(am[3], inv, b0.w));
        float4 o1 = make_float4(fmaf(am[4], inv, b1.x), fmaf(am[5], inv, b1.y),
                                fmaf(am[6], inv, b1.z), fmaf(am[7], inv, b1.w));
        size_t ob = (size_t)node * 40 + v * 8;
        *(float4*)&out[ob] = o0;
        *(float4*)&out[ob + 4] = o1;
    }
}

// ---------------------------------------------------------------------------
extern "C" void kernel_launch(void* const* d_in, const int* in_sizes, int n_in,
                              void* d_out, int out_size, void* d_ws, size_t ws_size,
                              hipStream_t stream) {
    const float* x   = (const float*)d_in[0];
    const int*   ei  = (const int*)d_in[1];
    const float* W1  = (const float*)d_in[2];
    const float* as1 = (const float*)d_in[3];
    const float* ad1 = (const float*)d_in[4];
    const float* b1  = (const float*)d_in[5];
    const float* W2  = (const float*)d_in[6];
    const float* as2 = (const float*)d_in[7];
    const float* ad2 = (const float*)d_in[8];
    const float* b2  = (const float*)d_in[9];

    int N = in_sizes[0] / 128;
    int E = in_sizes[1] / 2;
    int EN = E + N;
    size_t Np = (size_t)((N + 3) & ~3);
    size_t ENp = ((size_t)EN + 3) & ~3;

    float* ws = (float*)d_ws;
    unsigned int* out1h = (unsigned int*)ws; ws += Np * 64;  // hi bf16 pairs
    unsigned int* out1l = (unsigned int*)ws; ws += Np * 64;  // lo bf16 pairs
    unsigned int* h1A = (unsigned int*)ws; ws += Np * 32;    // ch 0-63, bf16x2
    unsigned int* h1Bp = (unsigned int*)ws; ws += Np * 32;   // ch 64-127
    unsigned int* h2b = (unsigned int*)ws; ws += Np * 32;    // padded 128 B rows
    float* a_src1  = ws; ws += Np * 8;
    float* a_dst1  = ws; ws += Np * 8;
    float* a_src2v = ws; ws += Np;
    float* a_dst2v = ws; ws += Np;
    bf16x8* Wp  = (bf16x8*)ws; ws += 2560 * 4;               // 40 KB repacked W1 + fused att
    bf16x8* W2p = (bf16x8*)ws; ws += 768 * 4;                // 12 KB repacked W2 (+fused)
    int* cnt    = (int*)ws; ws += Np;
    int* rowptr = (int*)ws; ws += Np + 4;
    int* psum   = (int*)ws; ws += 256;
    unsigned short* col  = (unsigned short*)ws; ws += ENp / 2 + 4;
    unsigned short* rank = (unsigned short*)ws; ws += ENp / 2 + 4;

    int nb = (N + 1023) / 1024;  // scan blocks (<=256)
    int npre = (N > 3328 ? N : 3328);

    k_prep<<<(npre + 255) / 256, 256, 0, stream>>>(W1, Wp, W2, W2p,
                                                   as1, ad1, as2, ad2, cnt, N);
    k_gemm1<<<(N + 63) / 64, 256, 0, stream>>>(x, Wp,
                                               (unsigned short*)h1A, (unsigned short*)h1Bp,
                                               a_src1, a_dst1, N);
    k_hist<<<(EN + 255) / 256, 256, 0, stream>>>(ei, E, N, cnt, rank);
    k_scan_part<<<nb, 256, 0, stream>>>(cnt, N, psum);
    k_scan_add<<<nb, 256, 0, stream>>>(cnt, N, psum, rowptr);
    k_scatter<<<(EN + 255) / 256, 256, 0, stream>>>(ei, E, N, rowptr, rank, col);

    int nag = (N + 7) / 8;
    k_aggr1<<<2 * nag, 256, 0, stream>>>(rowptr, cnt, col, a_src1, a_dst1,
                                         h1A, h1Bp, b1, out1h, out1l, N, nag);
    k_gemm2<<<(N + 63) / 64, 256, 0, stream>>>(out1h, out1l, W2p,
                                               (unsigned short*)h2b, a_src2v, a_dst2v, N);
    k_aggr2<<<nag, 256, 0, stream>>>(rowptr, cnt, col, a_src2v, a_dst2v, h2b, b2, (float*)d_out, N);
}